// Round 3
// baseline (79.043 us; speedup 1.0000x reference)
//
#include <hip/hip_runtime.h>

#define DIM 64

// CSR SpMM: out[i,:] = sum_{k in [indptr[i], indptr[i+1])} values[k] * x[indices[k],:]
// Persistent waves: one 64-lane wave handles rows {w, w+n_waves, ...}.
// Per row: 8-deep gather pipeline; next row's indptr prefetched before inner loop.
__global__ __launch_bounds__(256) void spmm_persistent_kernel(
    const float* __restrict__ x,
    const int*   __restrict__ indptr,
    const int*   __restrict__ indices,
    const float* __restrict__ values,
    float*       __restrict__ out,
    int n_nodes, int n_waves)
{
    const int lane = (int)(threadIdx.x & 63);
    int row = (int)((blockIdx.x * blockDim.x + threadIdx.x) >> 6);
    if (row >= n_nodes) return;

    int start = indptr[row];
    int end   = indptr[row + 1];

    while (true) {
        // Prefetch next row's extent early so its latency hides under this row's work.
        const int nrow = row + n_waves;
        int nstart = 0, nend = 0;
        if (nrow < n_nodes) {
            nstart = indptr[nrow];
            nend   = indptr[nrow + 1];
        }

        float acc = 0.0f;
        int k = start;

        // Alignment prologue: bring k to a multiple of 4 (for int4/float4 loads).
        while (k < end && (k & 3)) {
            acc += values[k] * x[(size_t)indices[k] * DIM + lane];
            ++k;
        }

        // 8-deep pipeline: 8 independent gathers in flight per wave.
        for (; k + 8 <= end; k += 8) {
            const int4   c0 = *(const int4*)  (indices + k);
            const int4   c1 = *(const int4*)  (indices + k + 4);
            const float4 v0 = *(const float4*)(values  + k);
            const float4 v1 = *(const float4*)(values  + k + 4);
            const float a0 = x[(size_t)c0.x * DIM + lane];
            const float a1 = x[(size_t)c0.y * DIM + lane];
            const float a2 = x[(size_t)c0.z * DIM + lane];
            const float a3 = x[(size_t)c0.w * DIM + lane];
            const float a4 = x[(size_t)c1.x * DIM + lane];
            const float a5 = x[(size_t)c1.y * DIM + lane];
            const float a6 = x[(size_t)c1.z * DIM + lane];
            const float a7 = x[(size_t)c1.w * DIM + lane];
            acc += v0.x * a0;
            acc += v0.y * a1;
            acc += v0.z * a2;
            acc += v0.w * a3;
            acc += v1.x * a4;
            acc += v1.y * a5;
            acc += v1.z * a6;
            acc += v1.w * a7;
        }

        // 4-deep tail
        if (k + 4 <= end) {
            const int4   c0 = *(const int4*)  (indices + k);
            const float4 v0 = *(const float4*)(values  + k);
            const float a0 = x[(size_t)c0.x * DIM + lane];
            const float a1 = x[(size_t)c0.y * DIM + lane];
            const float a2 = x[(size_t)c0.z * DIM + lane];
            const float a3 = x[(size_t)c0.w * DIM + lane];
            acc += v0.x * a0;
            acc += v0.y * a1;
            acc += v0.z * a2;
            acc += v0.w * a3;
            k += 4;
        }

        // scalar tail (<= 3 iterations)
        for (; k < end; ++k) {
            acc += values[k] * x[(size_t)indices[k] * DIM + lane];
        }

        out[(size_t)row * DIM + lane] = acc;   // coalesced 256B store

        if (nrow >= n_nodes) break;
        row   = nrow;
        start = nstart;
        end   = nend;
    }
}

extern "C" void kernel_launch(void* const* d_in, const int* in_sizes, int n_in,
                              void* d_out, int out_size, void* d_ws, size_t ws_size,
                              hipStream_t stream) {
    const float* x       = (const float*)d_in[0];
    const int*   indptr  = (const int*)  d_in[1];
    const int*   indices = (const int*)  d_in[2];
    const float* values  = (const float*)d_in[3];
    float*       out     = (float*)d_out;

    const int n_nodes = in_sizes[1] - 1;   // indptr has N+1 entries

    const int threads = 256;               // 4 waves/block
    const int blocks  = 2048;              // full residency: 8192 waves at VGPR<=64
    const int n_waves = blocks * (threads / 64);

    spmm_persistent_kernel<<<blocks, threads, 0, stream>>>(
        x, indptr, indices, values, out, n_nodes, n_waves);
}

// Round 4
// 61.750 us; speedup vs baseline: 1.2800x; 1.2800x over previous
//
#include <hip/hip_runtime.h>

#define DIM 64

// CSR SpMM: out[i,:] = sum_{k in [indptr[i], indptr[i+1])} values[k] * x[indices[k],:]
// One wave per row. Wave is split into 4 x 16-lane groups; each group handles a
// different edge, each lane holds 4 consecutive columns (float4). One
// global_load_dwordx4 moves 4 edges' x-rows (1 KiB) -> 4x bytes per vmem slot.
// Row-end: 2-round shfl_xor butterfly (masks 16,32) sums the 4 groups.
__global__ __launch_bounds__(256) void spmm_quad_kernel(
    const float* __restrict__ x,
    const int*   __restrict__ indptr,
    const int*   __restrict__ indices,
    const float* __restrict__ values,
    float*       __restrict__ out,
    int n_nodes)
{
    const int row  = (int)((blockIdx.x * blockDim.x + threadIdx.x) >> 6);
    const int lane = (int)(threadIdx.x & 63);
    if (row >= n_nodes) return;

    const int start = indptr[row];
    const int end   = indptr[row + 1];
    const int g     = lane >> 4;            // edge sub-slot 0..3
    const unsigned col4 = (unsigned)(lane & 15) << 2;  // this lane's 4 columns

    float ax = 0.f, ay = 0.f, az = 0.f, aw = 0.f;

    if (start < end) {
        const int last = end - 1;
        for (int k = start; k < end; k += 16) {
            // 16 edges in flight: 4 sub-batches of 4 edges (one per lane group)
            const int e0 = k +  0 + g;
            const int e1 = k +  4 + g;
            const int e2 = k +  8 + g;
            const int e3 = k + 12 + g;
            const int ce0 = e0 <= last ? e0 : last;
            const int ce1 = e1 <= last ? e1 : last;
            const int ce2 = e2 <= last ? e2 : last;
            const int ce3 = e3 <= last ? e3 : last;

            const int c0 = indices[ce0];
            const int c1 = indices[ce1];
            const int c2 = indices[ce2];
            const int c3 = indices[ce3];
            const float w0 = (e0 <= last) ? values[ce0] : 0.0f;
            const float w1 = (e1 <= last) ? values[ce1] : 0.0f;
            const float w2 = (e2 <= last) ? values[ce2] : 0.0f;
            const float w3 = (e3 <= last) ? values[ce3] : 0.0f;

            const float4 a0 = *(const float4*)(x + (((unsigned)c0) << 6) + col4);
            const float4 a1 = *(const float4*)(x + (((unsigned)c1) << 6) + col4);
            const float4 a2 = *(const float4*)(x + (((unsigned)c2) << 6) + col4);
            const float4 a3 = *(const float4*)(x + (((unsigned)c3) << 6) + col4);

            ax += w0 * a0.x; ay += w0 * a0.y; az += w0 * a0.z; aw += w0 * a0.w;
            ax += w1 * a1.x; ay += w1 * a1.y; az += w1 * a1.z; aw += w1 * a1.w;
            ax += w2 * a2.x; ay += w2 * a2.y; az += w2 * a2.z; aw += w2 * a2.w;
            ax += w3 * a3.x; ay += w3 * a3.y; az += w3 * a3.z; aw += w3 * a3.w;
        }
    }

    // Sum the 4 lane groups: lanes {l, l^16, l^32, l^48} hold the same columns.
    ax += __shfl_xor(ax, 16); ay += __shfl_xor(ay, 16);
    az += __shfl_xor(az, 16); aw += __shfl_xor(aw, 16);
    ax += __shfl_xor(ax, 32); ay += __shfl_xor(ay, 32);
    az += __shfl_xor(az, 32); aw += __shfl_xor(aw, 32);

    if (lane < 16) {
        float4 r; r.x = ax; r.y = ay; r.z = az; r.w = aw;
        *(float4*)(out + ((size_t)row << 6) + col4) = r;   // 256B row store
    }
}

extern "C" void kernel_launch(void* const* d_in, const int* in_sizes, int n_in,
                              void* d_out, int out_size, void* d_ws, size_t ws_size,
                              hipStream_t stream) {
    const float* x       = (const float*)d_in[0];
    const int*   indptr  = (const int*)  d_in[1];
    const int*   indices = (const int*)  d_in[2];
    const float* values  = (const float*)d_in[3];
    float*       out     = (float*)d_out;

    const int n_nodes = in_sizes[1] - 1;   // indptr has N+1 entries

    const int threads = 256;               // 4 waves/block -> 4 rows/block
    const int rows_per_block = threads / 64;
    const int blocks = (n_nodes + rows_per_block - 1) / rows_per_block;

    spmm_quad_kernel<<<blocks, threads, 0, stream>>>(
        x, indptr, indices, values, out, n_nodes);
}